// Round 1
// baseline (1175.359 us; speedup 1.0000x reference)
//
#include <hip/hip_runtime.h>
#include <hip/hip_bf16.h>
#include <stdint.h>

#define NTOK 8192
#define DM 2048
#define DH 2048
#define NEXP 8
#define TOPK 2
#define TASSIGN (NTOK * TOPK)   // 16384
#define CAP 2560                // int(1.25 * TOPK * NTOK / NEXP)
#define MROWS (NEXP * CAP)      // 20480
#define MTILES_PER_E (CAP / 128) // 20

using bf16x8 = __attribute__((ext_vector_type(8))) __bf16;
using bf16x2 = __attribute__((ext_vector_type(2))) __bf16;
using f32x4  = __attribute__((ext_vector_type(4))) float;

__device__ inline void load_lds16(const void* g, void* l) {
    __builtin_amdgcn_global_load_lds((const __attribute__((address_space(1))) void*)g,
                                     (__attribute__((address_space(3))) void*)l,
                                     16, 0, 0);
}

// ---------------- routing: stable per-expert ranks ----------------
__global__ void routing_kernel(const int* __restrict__ eidx,
                               int* __restrict__ counts,
                               int* __restrict__ slot_token,
                               int* __restrict__ assign_slot,
                               float* __restrict__ counts_out)
{
    __shared__ int base[NEXP];
    __shared__ int wcnt[4][NEXP];
    int tid = threadIdx.x, lane = tid & 63, wid = tid >> 6;
    for (int i = tid; i < MROWS; i += 256) slot_token[i] = -1;
    if (tid < NEXP) base[tid] = 0;
    __syncthreads();
    for (int t0 = 0; t0 < TASSIGN; t0 += 256) {
        int t = t0 + tid;
        int e = eidx[t];
        unsigned long long mymask = 0;
        #pragma unroll
        for (int ex = 0; ex < NEXP; ex++) {
            unsigned long long m = __ballot(e == ex);
            if (ex == e) mymask = m;
            if (lane == 0) wcnt[wid][ex] = __popcll(m);
        }
        int rankw = __popcll(mymask & ((1ull << lane) - 1ull));
        __syncthreads();
        int prev = base[e];
        for (int w = 0; w < wid; w++) prev += wcnt[w][e];
        int r = prev + rankw;
        int slot = (r < CAP) ? (e * CAP + r) : -1;
        assign_slot[t] = slot;
        if (slot >= 0) slot_token[slot] = t >> 1;  // token = assignment / TOPK
        __syncthreads();
        if (tid < NEXP) {
            int s = 0;
            for (int w = 0; w < 4; w++) s += wcnt[w][tid];
            base[tid] += s;
        }
        __syncthreads();
    }
    if (tid < NEXP) {
        counts[tid] = base[tid];
        counts_out[tid] = (float)base[tid];  // output 1 compared as float32
    }
}

// ---------------- weight transpose + fp32->bf16 convert ----------------
// src: [K=2048][N=2048] fp32 ; dst: [N][K] bf16
__global__ void transpose_kernel(const float* __restrict__ wa,
                                 const float* __restrict__ wb,
                                 const float* __restrict__ wc,
                                 __bf16* __restrict__ wat,
                                 __bf16* __restrict__ wbt,
                                 __bf16* __restrict__ wct)
{
    __shared__ float tile[64][65];
    int z = blockIdx.z;
    int mat = z >> 3, e = z & 7;
    const float* src = (mat == 0 ? wa : mat == 1 ? wb : wc) + (size_t)e * DM * DH;
    __bf16* dst = (mat == 0 ? wat : mat == 1 ? wbt : wct) + (size_t)e * DM * DH;
    int k0 = blockIdx.x * 64, n0 = blockIdx.y * 64;
    int tid = threadIdx.x;
    #pragma unroll
    for (int i = 0; i < 16; i++) {
        int lin = tid + i * 256;
        int r = lin >> 6, c = lin & 63;
        tile[r][c] = src[(size_t)(k0 + r) * DH + (n0 + c)];
    }
    __syncthreads();
    #pragma unroll
    for (int i = 0; i < 8; i++) {
        int lin = tid + i * 256;
        int r = lin >> 5, p = lin & 31;
        int c = p * 2;
        bf16x2 v;
        v[0] = (__bf16)tile[c][r];
        v[1] = (__bf16)tile[c + 1][r];
        *(bf16x2*)(dst + (size_t)(n0 + r) * DM + (k0 + c)) = v;
    }
}

// ---------------- gather x rows into padded bf16 bins ----------------
__global__ void gather_kernel(const float* __restrict__ x,
                              const int* __restrict__ slot_token,
                              __bf16* __restrict__ xg)
{
    int slot = blockIdx.x;
    int tok = slot_token[slot];
    int c = threadIdx.x * 8;
    float f[8];
    if (tok >= 0) {
        const float4* px = (const float4*)(x + (size_t)tok * DM + c);
        float4 a = px[0], b = px[1];
        f[0] = a.x; f[1] = a.y; f[2] = a.z; f[3] = a.w;
        f[4] = b.x; f[5] = b.y; f[6] = b.z; f[7] = b.w;
    } else {
        #pragma unroll
        for (int i = 0; i < 8; i++) f[i] = 0.f;
    }
    bf16x8 v;
    #pragma unroll
    for (int i = 0; i < 8; i++) v[i] = (__bf16)f[i];
    *(bf16x8*)(xg + (size_t)slot * DM + c) = v;
}

// ---------------- grouped GEMM, m97 structure ----------------
// A: [MROWS][K] bf16 row-major. B1/B2: [E][N][K] bf16 (pre-transposed).
// FUSED: C = silu(A@B1t) * (A@B2t); else C = A@B1t. C bf16 [MROWS][N].
template<bool FUSED>
__global__ __launch_bounds__(256, 2)
void gemm_kernel(const __bf16* __restrict__ A,
                 const __bf16* __restrict__ B1,
                 const __bf16* __restrict__ B2,
                 __bf16* __restrict__ C,
                 const int* __restrict__ counts)
{
    constexpr int K = 2048, N = 2048, BM = 128, BN = 128, BK = 32;
    __shared__ __bf16 As[BM * BK];
    __shared__ __bf16 Bs1[BN * BK];
    __shared__ __bf16 Bs2[FUSED ? BN * BK : 8];

    int mtile = blockIdx.x, ntile = blockIdx.y;
    int e = mtile / MTILES_PER_E;
    int mloc = (mtile % MTILES_PER_E) * BM;
    int rows = counts[e]; rows = rows > CAP ? CAP : rows;
    if (mloc >= rows) return;   // expert bin has no rows in this tile

    int tid = threadIdx.x, lane = tid & 63, wid = tid >> 6;
    size_t rowBase = (size_t)e * CAP + mloc;

    // staging: wave wid covers rows [32*wid, 32*wid+32), lane -> (row=lane/4, chunk=lane%4)
    const __bf16* aG  = A + (rowBase + wid * 32 + (lane >> 2)) * K + (lane & 3) * 8;
    const __bf16* aG2 = aG + (size_t)16 * K;
    __bf16* aL  = As + (wid * 32) * BK;
    __bf16* aL2 = aL + 16 * BK;

    size_t bRow = (size_t)e * N + (size_t)ntile * BN + wid * 32 + (lane >> 2);
    const __bf16* b1G  = B1 + bRow * K + (lane & 3) * 8;
    const __bf16* b1G2 = b1G + (size_t)16 * K;
    __bf16* b1L  = Bs1 + (wid * 32) * BK;
    __bf16* b1L2 = b1L + 16 * BK;
    const __bf16* b2G  = FUSED ? (B2 + bRow * K + (lane & 3) * 8) : (const __bf16*)nullptr;
    __bf16* b2L  = Bs2 + (wid * 32) * BK;

    // MFMA fragment read pointers (fixed across K iterations)
    int wm = wid & 1, wn = wid >> 1;
    const __bf16* aF  = As  + (wm * 64 + (lane & 15)) * BK + (lane >> 4) * 8;
    const __bf16* b1F = Bs1 + (wn * 64 + (lane & 15)) * BK + (lane >> 4) * 8;
    const __bf16* b2F = Bs2 + (wn * 64 + (lane & 15)) * BK + (lane >> 4) * 8;

    f32x4 acc1[4][4];
    f32x4 acc2[FUSED ? 4 : 1][4];
    #pragma unroll
    for (int i = 0; i < 4; i++)
        #pragma unroll
        for (int j = 0; j < 4; j++) {
            acc1[i][j] = (f32x4){0.f, 0.f, 0.f, 0.f};
            if (FUSED) acc2[i][j] = (f32x4){0.f, 0.f, 0.f, 0.f};
        }

    for (int k0 = 0; k0 < K; k0 += BK) {
        load_lds16(aG + k0, aL);
        load_lds16(aG2 + k0, aL2);
        load_lds16(b1G + k0, b1L);
        load_lds16(b1G2 + k0, b1L2);
        if constexpr (FUSED) {
            load_lds16(b2G + k0, b2L);
            load_lds16(b2G + k0 + (size_t)16 * K, b2L + 16 * BK);
        }
        __syncthreads();

        bf16x8 a[4], b1v[4];
        #pragma unroll
        for (int i = 0; i < 4; i++) a[i]   = *(const bf16x8*)(aF + i * 16 * BK);
        #pragma unroll
        for (int j = 0; j < 4; j++) b1v[j] = *(const bf16x8*)(b1F + j * 16 * BK);
        #pragma unroll
        for (int i = 0; i < 4; i++)
            #pragma unroll
            for (int j = 0; j < 4; j++)
                acc1[i][j] = __builtin_amdgcn_mfma_f32_16x16x32_bf16(a[i], b1v[j], acc1[i][j], 0, 0, 0);
        if constexpr (FUSED) {
            bf16x8 b2v[4];
            #pragma unroll
            for (int j = 0; j < 4; j++) b2v[j] = *(const bf16x8*)(b2F + j * 16 * BK);
            #pragma unroll
            for (int i = 0; i < 4; i++)
                #pragma unroll
                for (int j = 0; j < 4; j++)
                    acc2[i][j] = __builtin_amdgcn_mfma_f32_16x16x32_bf16(a[i], b2v[j], acc2[i][j], 0, 0, 0);
        }
        __syncthreads();
    }

    // epilogue: C/D layout col = lane&15, row = (lane>>4)*4 + reg
    size_t row0 = rowBase + wm * 64 + (lane >> 4) * 4;
    int col0 = ntile * BN + wn * 64 + (lane & 15);
    #pragma unroll
    for (int i = 0; i < 4; i++)
        #pragma unroll
        for (int j = 0; j < 4; j++)
            #pragma unroll
            for (int r = 0; r < 4; r++) {
                float v = acc1[i][j][r];
                if constexpr (FUSED) {
                    float z3 = acc2[i][j][r];
                    v = (v / (1.f + __expf(-v))) * z3;   // silu(z1) * z3
                }
                C[(row0 + i * 16 + r) * N + (col0 + j * 16)] = (__bf16)v;
            }
}

// ---------------- weighted combine back to tokens ----------------
__global__ void combine_kernel(const __bf16* __restrict__ y,
                               const int* __restrict__ assign_slot,
                               const float* __restrict__ ew,
                               float* __restrict__ out)
{
    int n = blockIdx.x;
    int s0 = assign_slot[2 * n], s1 = assign_slot[2 * n + 1];
    float w0 = ew[2 * n], w1 = ew[2 * n + 1];
    int c = threadIdx.x * 8;
    float acc[8];
    #pragma unroll
    for (int i = 0; i < 8; i++) acc[i] = 0.f;
    if (s0 >= 0) {
        bf16x8 v = *(const bf16x8*)(y + (size_t)s0 * DM + c);
        #pragma unroll
        for (int i = 0; i < 8; i++) acc[i] += w0 * (float)v[i];
    }
    if (s1 >= 0) {
        bf16x8 v = *(const bf16x8*)(y + (size_t)s1 * DM + c);
        #pragma unroll
        for (int i = 0; i < 8; i++) acc[i] += w1 * (float)v[i];
    }
    float4* po = (float4*)(out + (size_t)n * DM + c);
    po[0] = (float4){acc[0], acc[1], acc[2], acc[3]};
    po[1] = (float4){acc[4], acc[5], acc[6], acc[7]};
}

extern "C" void kernel_launch(void* const* d_in, const int* in_sizes, int n_in,
                              void* d_out, int out_size, void* d_ws, size_t ws_size,
                              hipStream_t stream)
{
    const float* x  = (const float*)d_in[0];
    const float* ew = (const float*)d_in[1];
    const int* eidx = (const int*)d_in[2];
    const float* w1 = (const float*)d_in[3];
    const float* w2 = (const float*)d_in[4];
    const float* w3 = (const float*)d_in[5];
    float* out = (float*)d_out;
    float* counts_out = out + (size_t)NTOK * DM;

    char* ws = (char*)d_ws;
    size_t off = 0;
    auto alloc = [&](size_t bytes) -> void* {
        off = (off + 255) & ~(size_t)255;
        void* p = ws + off;
        off += bytes;
        return p;
    };
    int* slot_token  = (int*)alloc((size_t)MROWS * 4);
    int* assign_slot = (int*)alloc((size_t)TASSIGN * 4);
    int* counts      = (int*)alloc(NEXP * 4);
    __bf16* xg  = (__bf16*)alloc((size_t)MROWS * DM * 2);
    __bf16* h   = (__bf16*)alloc((size_t)MROWS * DH * 2);
    __bf16* w1t = (__bf16*)alloc((size_t)NEXP * DM * DH * 2);
    __bf16* w3t = (__bf16*)alloc((size_t)NEXP * DM * DH * 2);
    __bf16* w2t = (__bf16*)alloc((size_t)NEXP * DM * DH * 2);
    __bf16* y = xg;  // xg dead after gemm1 -> reuse for y

    routing_kernel<<<1, 256, 0, stream>>>(eidx, counts, slot_token, assign_slot, counts_out);
    transpose_kernel<<<dim3(32, 32, 24), 256, 0, stream>>>(w1, w3, w2, w1t, w3t, w2t);
    gather_kernel<<<MROWS, 256, 0, stream>>>(x, slot_token, xg);
    gemm_kernel<true><<<dim3(160, 16), 256, 0, stream>>>(xg, w1t, w3t, h, counts);
    gemm_kernel<false><<<dim3(160, 16), 256, 0, stream>>>(h, w2t, nullptr, y, counts);
    combine_kernel<<<NTOK, 256, 0, stream>>>(y, assign_slot, ew, out);
}